// Round 1
// baseline (1411.895 us; speedup 1.0000x reference)
//
#include <hip/hip_runtime.h>
#include <math.h>

#define NPTS 4096
#define CDIM 128
#define FH 120
#define FW 160

// workspace layout (float offsets)
#define OFF_D1   0
#define OFF_WD   (2*NPTS*CDIM)               // 1048576
#define OFF_ND1  (2*OFF_WD)                  // 2097152
#define OFF_NWD  (OFF_ND1 + 2*NPTS)
#define OFF_POS  (OFF_NWD + 2*NPTS)
#define OFF_VIS  (OFF_POS + 2*NPTS)
#define OFF_ACC  (OFF_VIS + 2*NPTS)

__device__ __forceinline__ float blocksum128(float v, volatile float* red) {
#pragma unroll
  for (int off = 32; off >= 1; off >>= 1) v += __shfl_down(v, off, 64);
  __syncthreads();  // protect red from previous use
  if ((threadIdx.x & 63) == 0) red[threadIdx.x >> 6] = v;
  __syncthreads();
  return red[0] + red[1];
}

__global__ __launch_bounds__(128) void prep_kernel(
    const float* __restrict__ kp1, const float* __restrict__ wkp1,
    const float* __restrict__ desc, const float* __restrict__ desc2,
    const float* __restrict__ homo,
    float* __restrict__ d1, float* __restrict__ wd,
    float* __restrict__ nd1, float* __restrict__ nwd,
    float* __restrict__ pos, float* __restrict__ vis) {
  __shared__ float red[2];
  const int p = blockIdx.x;           // 0..8191
  const int b = p >> 12;              // /4096
  const int c = threadIdx.x;          // 0..127

  // ---- d1 = l2n(kp1_desc) ----
  float v = desc[(size_t)p * CDIM + c];
  float ss = blocksum128(v * v, red);
  float inv = 1.0f / (sqrtf(ss) + 1e-8f);
  float dv = v * inv;
  d1[(size_t)p * CDIM + c] = dv;
  if (c == 0) nd1[p] = ss * inv * inv;

  // ---- bilinear sample of desc2 at w_kp1 ----
  float y = wkp1[p * 2 + 0], x = wkp1[p * 2 + 1];
  float gy = fminf(fmaxf(y * 0.125f - 0.5f, 0.0f), (float)(FH - 1));
  float gx = fminf(fmaxf(x * 0.125f - 0.5f, 0.0f), (float)(FW - 1));
  int y0 = (int)floorf(gy); y0 = min(max(y0, 0), FH - 2);
  int x0 = (int)floorf(gx); x0 = min(max(x0, 0), FW - 2);
  float wy = gy - (float)y0, wx = gx - (float)x0;
  const float* dbase = desc2 + ((size_t)b * CDIM + c) * (FH * FW) + y0 * FW + x0;
  float v00 = dbase[0], v01 = dbase[1], v10 = dbase[FW], v11 = dbase[FW + 1];
  float wv = v00 * (1.0f - wy) * (1.0f - wx) + v01 * (1.0f - wy) * wx
           + v10 * wy * (1.0f - wx) + v11 * wy * wx;
  float ss2 = blocksum128(wv * wv, red);
  float inv2 = 1.0f / (sqrtf(ss2) + 1e-8f);
  float wdv = wv * inv2;
  wd[(size_t)p * CDIM + c] = wdv;
  if (c == 0) nwd[p] = ss2 * inv2 * inv2;

  // ---- pos = ||d1 - w_desc|| ----
  float d = dv - wdv;
  float ssp = blocksum128(d * d, red);
  if (c == 0) pos[p] = sqrtf(ssp + 1e-12f);

  // ---- visibility ----
  if (c == 0) {
    float yy = kp1[p * 2 + 0], xx = kp1[p * 2 + 1];
    const float* h = homo + b * 9;
    float q0 = h[0] * xx + h[1] * yy + h[2];
    float q1 = h[3] * xx + h[4] * yy + h[5];
    float q2 = h[6] * xx + h[7] * yy + h[8];
    float qx = q0 / (q2 + 1e-8f);
    float qy = q1 / (q2 + 1e-8f);
    vis[p] = (qx >= 0.0f && qx < 1280.0f && qy >= 0.0f && qy < 960.0f) ? 1.0f : 0.0f;
  }
}

__device__ __forceinline__ void dot4(float& acc, const float4 a, const float4 b) {
  acc = fmaf(a.x, b.x, acc);
  acc = fmaf(a.y, b.y, acc);
  acc = fmaf(a.z, b.z, acc);
  acc = fmaf(a.w, b.w, acc);
}

// insert v into ascending 4-list (drops largest)
__device__ __forceinline__ void ins4(float v, float* L) {
  if (v < L[3]) {
    float cv = v;
#pragma unroll
    for (int k = 0; k < 4; ++k) {
      float o = L[k];
      bool lt = cv < o;
      L[k] = lt ? cv : o;
      cv = lt ? o : cv;
    }
  }
}

// insert (v,p) into ascending 8-list keyed by v (drops largest)
__device__ __forceinline__ void ins8(float v, float p, float* S, float* P) {
  if (v < S[7]) {
    float cv = v, cp = p;
#pragma unroll
    for (int k = 0; k < 8; ++k) {
      float os = S[k], op = P[k];
      bool lt = cv < os;
      S[k] = lt ? cv : os;
      P[k] = lt ? cp : op;
      cv = lt ? os : cv;
      cp = lt ? op : cp;
    }
  }
}

// 1024 blocks x 256 threads; block = (batch, 8 rows), sweeps all 4096 cols.
__global__ __launch_bounds__(256, 3) void loss_main(
    const float* __restrict__ kp1, const float* __restrict__ wkp1,
    const float* __restrict__ d1g, const float* __restrict__ wdg,
    const float* __restrict__ nd1g, const float* __restrict__ nwdg,
    const float* __restrict__ posg, const float* __restrict__ visg,
    float* __restrict__ accum) {
  __shared__ float jd1[128 * 20];   // [col][16c chunk, padded to 20]
  __shared__ float jwd[128 * 20];
  __shared__ float id1[8 * 132];    // [row][128c padded to 132]
  __shared__ float iwd[8 * 132];
  __shared__ float jn1[128], jn2[128];
  __shared__ float jkp[256], jwkp[256];

  const int tid = threadIdx.x;
  const int b = blockIdx.x & 1;          // batch parity-swizzled across XCDs
  const int rb = blockIdx.x >> 1;        // 0..511
  const int i0 = rb * 8;
  const int ti = tid >> 6;               // wave id -> row pair
  const int jl = tid & 63;
  const int ca = jl, cb = jl + 64;       // this thread's two columns in the tile
  const int base = b * NPTS;

  // stage i-side descriptors (8 rows x 128c, float4)
  {
    int r = tid >> 5, c4 = tid & 31;
    const float4* s1 = (const float4*)(d1g + (size_t)(base + i0 + r) * CDIM);
    const float4* s2 = (const float4*)(wdg + (size_t)(base + i0 + r) * CDIM);
    ((float4*)id1)[r * 33 + c4] = s1[c4];
    ((float4*)iwd)[r * 33 + c4] = s2[c4];
  }
  const int gr0 = base + i0 + ti * 2, gr1 = gr0 + 1;
  const float ky0 = kp1[gr0 * 2], kx0 = kp1[gr0 * 2 + 1];
  const float ky1 = kp1[gr1 * 2], kx1 = kp1[gr1 * 2 + 1];
  const float wyk0 = wkp1[gr0 * 2], wxk0 = wkp1[gr0 * 2 + 1];
  const float wyk1 = wkp1[gr1 * 2], wxk1 = wkp1[gr1 * 2 + 1];
  const float n1i0 = nd1g[gr0], n1i1 = nd1g[gr1];
  const float n2i0 = nwdg[gr0], n2i1 = nwdg[gr1];

  // topk state: [row-of-pair][k]; BIG=5 init reproduces mask-fill; HUGE=1e6 reproduces padding
  float LD[2][4], LDt[2][4], SS[2][8], SP[2][8];
#pragma unroll
  for (int r = 0; r < 2; ++r) {
#pragma unroll
    for (int k = 0; k < 4; ++k) { LD[r][k] = 5.0f; LDt[r][k] = 5.0f; }
#pragma unroll
    for (int k = 0; k < 8; ++k) { SS[r][k] = 1e6f; SP[r][k] = 0.0f; }
  }

  const int r0l = ti * 2, r1l = r0l + 1;

  for (int jt = 0; jt < 32; ++jt) {
    const int jb = jt * 128;
    __syncthreads();  // prev tile's compute+topk done before restaging
    if (tid < 128) {
      int gj = base + jb + tid;
      jkp[tid * 2] = kp1[gj * 2];
      jkp[tid * 2 + 1] = kp1[gj * 2 + 1];
      jn1[tid] = nd1g[gj];
    } else {
      int t2 = tid & 127;
      int gj = base + jb + t2;
      jwkp[t2 * 2] = wkp1[gj * 2];
      jwkp[t2 * 2 + 1] = wkp1[gj * 2 + 1];
      jn2[t2] = nwdg[gj];
    }
    float aD[4] = {0, 0, 0, 0}, aDt[4] = {0, 0, 0, 0};
    float a11[4] = {0, 0, 0, 0}, a22[4] = {0, 0, 0, 0};
    for (int q = 0; q < 8; ++q) {  // 8 chunks of 16 channels
      if (q) __syncthreads();
      for (int g = tid; g < 512; g += 256) {
        int col = g >> 2, cg = g & 3;
        size_t gofs = (size_t)(base + jb + col) * CDIM + q * 16;
        ((float4*)jd1)[col * 5 + cg] = *(const float4*)(d1g + gofs + cg * 4);
        ((float4*)jwd)[col * 5 + cg] = *(const float4*)(wdg + gofs + cg * 4);
      }
      __syncthreads();
      const float4* J1 = (const float4*)jd1;
      const float4* J2 = (const float4*)jwd;
      const float4* I1 = (const float4*)id1;
      const float4* I2 = (const float4*)iwd;
#pragma unroll
      for (int c4 = 0; c4 < 4; ++c4) {
        float4 ja0 = J1[ca * 5 + c4], ja1 = J1[cb * 5 + c4];
        float4 jw0 = J2[ca * 5 + c4], jw1 = J2[cb * 5 + c4];
        float4 ia0 = I1[r0l * 33 + q * 4 + c4], ia1 = I1[r1l * 33 + q * 4 + c4];
        float4 iw0 = I2[r0l * 33 + q * 4 + c4], iw1 = I2[r1l * 33 + q * 4 + c4];
        dot4(aD[0], ia0, jw0);  dot4(aD[1], ia0, jw1);
        dot4(aD[2], ia1, jw0);  dot4(aD[3], ia1, jw1);
        dot4(aDt[0], iw0, ja0); dot4(aDt[1], iw0, ja1);
        dot4(aDt[2], iw1, ja0); dot4(aDt[3], iw1, ja1);
        dot4(a11[0], ia0, ja0); dot4(a11[1], ia0, ja1);
        dot4(a11[2], ia1, ja0); dot4(a11[3], ia1, ja1);
        dot4(a22[0], iw0, jw0); dot4(a22[1], iw0, jw1);
        dot4(a22[2], iw1, jw0); dot4(a22[3], iw1, jw1);
      }
    }
    // ---- topk updates for the 4 (row,col) pairs ----
#pragma unroll
    for (int pp = 0; pp < 4; ++pp) {
      const int r = pp >> 1;
      const int cl = (pp & 1) ? cb : ca;
      const float kiy = r ? ky1 : ky0, kix = r ? kx1 : kx0;
      const float wiy = r ? wyk1 : wyk0, wix = r ? wxk1 : wxk0;
      const float ndi = r ? n1i1 : n1i0, nwi = r ? n2i1 : n2i0;
      float dy = kiy - jkp[cl * 2], dx = kix - jkp[cl * 2 + 1];
      float s11 = dy * dy + dx * dx;
      float wdy = wiy - jwkp[cl * 2], wdx = wix - jwkp[cl * 2 + 1];
      float s22 = wdy * wdy + wdx * wdx;
      if (s22 > 256.0f) {  // not radius-masked (r=16, squared compare exact)
        float nj1 = jn1[cl], nj2 = jn2[cl];
        float dD = sqrtf(fmaxf(ndi + nj2 - 2.0f * aD[pp], 1e-12f));
        ins4(dD, LD[r]);
        float dDt = sqrtf(fmaxf(nwi + nj1 - 2.0f * aDt[pp], 1e-12f));
        ins4(dDt, LDt[r]);
        if (s11 > 256.0f) {  // SOS-valid
          float d11v = sqrtf(fmaxf(ndi + nj1 - 2.0f * a11[pp], 1e-12f));
          if (d11v < SS[r][7]) {
            float d22v = sqrtf(fmaxf(nwi + nj2 - 2.0f * a22[pp], 1e-12f));
            ins8(d11v, d22v, SS[r], SP[r]);
          }
        }
      }
    }
  }

  // ---- wave butterfly merge (64 lanes) ----
  for (int off = 1; off < 64; off <<= 1) {
#pragma unroll
    for (int r = 0; r < 2; ++r) {
      float tv[8], tp[8];
#pragma unroll
      for (int k = 0; k < 4; ++k) tv[k] = __shfl_xor(LD[r][k], off, 64);
#pragma unroll
      for (int k = 0; k < 4; ++k) ins4(tv[k], LD[r]);
#pragma unroll
      for (int k = 0; k < 4; ++k) tv[k] = __shfl_xor(LDt[r][k], off, 64);
#pragma unroll
      for (int k = 0; k < 4; ++k) ins4(tv[k], LDt[r]);
#pragma unroll
      for (int k = 0; k < 8; ++k) {
        tv[k] = __shfl_xor(SS[r][k], off, 64);
        tp[k] = __shfl_xor(SP[r][k], off, 64);
      }
#pragma unroll
      for (int k = 0; k < 8; ++k) ins8(tv[k], tp[k], SS[r], SP[r]);
    }
  }

  // ---- epilogue: lane 0 of each wave accumulates its two rows ----
  if ((tid & 63) == 0) {
    float contrib = 0.0f;
#pragma unroll
    for (int r = 0; r < 2; ++r) {
      int gi = gr0 + r;
      float pv = posg[gi], vv = visg[gi];
      float t1s = 0.0f, t2s = 0.0f;
#pragma unroll
      for (int k = 0; k < 4; ++k) {
        t1s += fmaxf(1.0f + pv - LD[r][k], 0.0f);
        t2s += fmaxf(1.0f + pv - LDt[r][k], 0.0f);
      }
      float s = 0.0f;
#pragma unroll
      for (int k = 0; k < 8; ++k) {
        float d = SS[r][k] - SP[r][k];
        s += (SS[r][k] < 1e5f) ? d * d : 0.0f;
      }
      contrib += vv * (0.125f * (t1s + t2s) + sqrtf(s + 1e-12f));
    }
    atomicAdd(&accum[0], contrib);
  }
}

__global__ __launch_bounds__(256) void finalize_kernel(
    const float* __restrict__ vis, const float* __restrict__ acc,
    float* __restrict__ out) {
  __shared__ float red[4];
  float s = 0.0f;
  for (int i = threadIdx.x; i < 2 * NPTS; i += 256) s += vis[i];
#pragma unroll
  for (int off = 32; off >= 1; off >>= 1) s += __shfl_down(s, off, 64);
  if ((threadIdx.x & 63) == 0) red[threadIdx.x >> 6] = s;
  __syncthreads();
  if (threadIdx.x == 0) {
    float denom = red[0] + red[1] + red[2] + red[3] + 1e-8f;
    out[0] = acc[0] / denom;
  }
}

extern "C" void kernel_launch(void* const* d_in, const int* in_sizes, int n_in,
                              void* d_out, int out_size, void* d_ws, size_t ws_size,
                              hipStream_t stream) {
  (void)in_sizes; (void)n_in; (void)out_size; (void)ws_size;
  const float* kp1   = (const float*)d_in[0];
  const float* wkp1  = (const float*)d_in[1];
  const float* desc  = (const float*)d_in[2];
  const float* desc2 = (const float*)d_in[3];
  const float* homo  = (const float*)d_in[4];
  float* ws  = (float*)d_ws;
  float* d1  = ws + OFF_D1;
  float* wd  = ws + OFF_WD;
  float* nd1 = ws + OFF_ND1;
  float* nwd = ws + OFF_NWD;
  float* pos = ws + OFF_POS;
  float* vis = ws + OFF_VIS;
  float* acc = ws + OFF_ACC;

  hipMemsetAsync(acc, 0, 2 * sizeof(float), stream);
  prep_kernel<<<2 * NPTS, 128, 0, stream>>>(kp1, wkp1, desc, desc2, homo,
                                            d1, wd, nd1, nwd, pos, vis);
  loss_main<<<1024, 256, 0, stream>>>(kp1, wkp1, d1, wd, nd1, nwd, pos, vis, acc);
  finalize_kernel<<<1, 256, 0, stream>>>(vis, acc, (float*)d_out);
}

// Round 2
// 313.385 us; speedup vs baseline: 4.5053x; 4.5053x over previous
//
#include <hip/hip_runtime.h>
#include <math.h>

#define NPTS 4096
#define CDIM 128
#define FH 120
#define FW 160

typedef __attribute__((ext_vector_type(8))) short short8_t;
typedef __attribute__((ext_vector_type(4))) float float4_t;

// workspace layout (float offsets)
#define OFF_D1B  0                    // 2*4096*128 ushort = 524288 floats
#define OFF_WDB  524288
#define OFF_JA   1048576              // float4 per point: 32768 floats
#define OFF_JB   1081344              // float2 per point: 16384 floats
#define OFF_POS  1097728              // 8192
#define OFF_VIS  1105920              // 8192
#define OFF_ACC  1114112              // 2

__device__ __forceinline__ float blocksum128(float v, volatile float* red) {
#pragma unroll
  for (int off = 32; off >= 1; off >>= 1) v += __shfl_down(v, off, 64);
  __syncthreads();
  if ((threadIdx.x & 63) == 0) red[threadIdx.x >> 6] = v;
  __syncthreads();
  return red[0] + red[1];
}

__device__ __forceinline__ unsigned short f2bf(float f) {
  unsigned int u = __float_as_uint(f);
  u = (u + 0x7fffu + ((u >> 16) & 1u)) >> 16;  // RNE (no NaN in this data)
  return (unsigned short)u;
}

__global__ __launch_bounds__(128) void prep_kernel(
    const float* __restrict__ kp1, const float* __restrict__ wkp1,
    const float* __restrict__ desc, const float* __restrict__ desc2,
    const float* __restrict__ homo,
    unsigned short* __restrict__ d1b, unsigned short* __restrict__ wdb,
    float4* __restrict__ jA, float2* __restrict__ jB,
    float* __restrict__ pos, float* __restrict__ vis) {
  __shared__ float red[2];
  const int p = blockIdx.x;           // 0..8191
  const int b = p >> 12;
  const int c = threadIdx.x;          // 0..127

  // ---- d1 = l2n(kp1_desc) ----
  float v = desc[(size_t)p * CDIM + c];
  float ss = blocksum128(v * v, red);
  float inv = 1.0f / (sqrtf(ss) + 1e-8f);
  float dv = v * inv;
  d1b[(size_t)p * CDIM + c] = f2bf(dv);
  float n1 = ss * inv * inv;

  // ---- bilinear sample of desc2 at w_kp1, then l2n ----
  float y = wkp1[p * 2 + 0], x = wkp1[p * 2 + 1];
  float gy = fminf(fmaxf(y * 0.125f - 0.5f, 0.0f), (float)(FH - 1));
  float gx = fminf(fmaxf(x * 0.125f - 0.5f, 0.0f), (float)(FW - 1));
  int y0 = (int)floorf(gy); y0 = min(max(y0, 0), FH - 2);
  int x0 = (int)floorf(gx); x0 = min(max(x0, 0), FW - 2);
  float wy = gy - (float)y0, wx = gx - (float)x0;
  const float* dbase = desc2 + ((size_t)b * CDIM + c) * (FH * FW) + y0 * FW + x0;
  float v00 = dbase[0], v01 = dbase[1], v10 = dbase[FW], v11 = dbase[FW + 1];
  float wv = v00 * (1.0f - wy) * (1.0f - wx) + v01 * (1.0f - wy) * wx
           + v10 * wy * (1.0f - wx) + v11 * wy * wx;
  float ss2 = blocksum128(wv * wv, red);
  float inv2 = 1.0f / (sqrtf(ss2) + 1e-8f);
  float wdv = wv * inv2;
  wdb[(size_t)p * CDIM + c] = f2bf(wdv);
  float n2 = ss2 * inv2 * inv2;

  // ---- pos = ||d1 - w_desc|| (fp32) ----
  float d = dv - wdv;
  float ssp = blocksum128(d * d, red);

  if (c == 0) {
    pos[p] = sqrtf(ssp + 1e-12f);
    float ky = kp1[p * 2 + 0], kx = kp1[p * 2 + 1];
    jA[p] = make_float4(ky, kx, y, x);     // (ky, kx, wky, wkx)
    jB[p] = make_float2(n1, n2);
    const float* h = homo + b * 9;
    float q0 = h[0] * kx + h[1] * ky + h[2];
    float q1 = h[3] * kx + h[4] * ky + h[5];
    float q2 = h[6] * kx + h[7] * ky + h[8];
    float qx = q0 / (q2 + 1e-8f);
    float qy = q1 / (q2 + 1e-8f);
    vis[p] = (qx >= 0.0f && qx < 1280.0f && qy >= 0.0f && qy < 960.0f) ? 1.0f : 0.0f;
  }
}

// insert v into ascending 4-list (drops largest)
__device__ __forceinline__ void ins4(float v, float* L) {
  if (v < L[3]) {
    float cv = v;
#pragma unroll
    for (int k = 0; k < 4; ++k) {
      float o = L[k];
      bool lt = cv < o;
      L[k] = lt ? cv : o;
      cv = lt ? o : cv;
    }
  }
}

// insert (v,p) into ascending 8-list keyed by v (drops largest)
__device__ __forceinline__ void ins8(float v, float p, float* S, float* P) {
  if (v < S[7]) {
    float cv = v, cp = p;
#pragma unroll
    for (int k = 0; k < 8; ++k) {
      float os = S[k], op = P[k];
      bool lt = cv < os;
      S[k] = lt ? cv : os;
      P[k] = lt ? cp : op;
      cv = lt ? os : cv;
      cp = lt ? op : cp;
    }
  }
}

// 512 blocks x 256 threads. block = (batch, 16 anchor rows); wave w sweeps
// j in [w*1024, (w+1)*1024). MFMA 16x16x32 bf16, top-k kept in squared space.
__global__ __launch_bounds__(256, 2) void loss_main(
    const unsigned short* __restrict__ d1b, const unsigned short* __restrict__ wdb,
    const float4* __restrict__ jA, const float2* __restrict__ jB,
    const float* __restrict__ posg, const float* __restrict__ visg,
    float* __restrict__ accum) {
  __shared__ float mergebuf[16 * 4 * 24];  // [row][wave][LD4|LDt4|SS8|SP8]

  const int tid = threadIdx.x;
  const int b = blockIdx.x & 1;
  const int g = blockIdx.x >> 1;     // 0..255
  const int i0 = g * 16;
  const int wave = tid >> 6, lane = tid & 63;
  const int c = lane & 15, quad = lane >> 4;
  const int base = b * NPTS;

  // ---- A fragments (16 rows, both descriptor sets), kept in registers ----
  short8_t Ad[4], Aw[4];
  {
    const unsigned short* pa = d1b + (size_t)(base + i0 + c) * CDIM + quad * 8;
    const unsigned short* pw = wdb + (size_t)(base + i0 + c) * CDIM + quad * 8;
#pragma unroll
    for (int kc = 0; kc < 4; ++kc) {
      Ad[kc] = *(const short8_t*)(pa + kc * 32);
      Aw[kc] = *(const short8_t*)(pw + kc * 32);
    }
  }
  // per-lane row info: rows quad*4+reg
  float4 iA[4]; float2 iB[4];
#pragma unroll
  for (int reg = 0; reg < 4; ++reg) {
    int gi = base + i0 + quad * 4 + reg;
    iA[reg] = jA[gi];
    iB[reg] = jB[gi];
  }

  // top-k state in SQUARED space. BIG^2=25 fill, HUGE-ish 1e12 fill.
  float LD[4][4], LDt[4][4], SS[4][8], SP[4][8];
#pragma unroll
  for (int r = 0; r < 4; ++r) {
#pragma unroll
    for (int k = 0; k < 4; ++k) { LD[r][k] = 25.0f; LDt[r][k] = 25.0f; }
#pragma unroll
    for (int k = 0; k < 8; ++k) { SS[r][k] = 1e12f; SP[r][k] = 0.0f; }
  }

  const int jq = wave * 1024;
  for (int t = 0; t < 64; ++t) {
    const int j0 = base + jq + t * 16;
    const unsigned short* pb1 = d1b + (size_t)(j0 + c) * CDIM + quad * 8;
    const unsigned short* pb2 = wdb + (size_t)(j0 + c) * CDIM + quad * 8;
    short8_t Bd[4], Bw[4];
#pragma unroll
    for (int kc = 0; kc < 4; ++kc) {
      Bd[kc] = *(const short8_t*)(pb1 + kc * 32);
      Bw[kc] = *(const short8_t*)(pb2 + kc * 32);
    }
    const float4 jA4 = jA[j0 + c];
    const float2 jB2 = jB[j0 + c];

    float4_t aD = {0, 0, 0, 0}, aDt = {0, 0, 0, 0};
    float4_t a11 = {0, 0, 0, 0}, a22 = {0, 0, 0, 0};
#pragma unroll
    for (int kc = 0; kc < 4; ++kc) {
      aD  = __builtin_amdgcn_mfma_f32_16x16x32_bf16(Ad[kc], Bw[kc], aD, 0, 0, 0);
      aDt = __builtin_amdgcn_mfma_f32_16x16x32_bf16(Aw[kc], Bd[kc], aDt, 0, 0, 0);
      a11 = __builtin_amdgcn_mfma_f32_16x16x32_bf16(Ad[kc], Bd[kc], a11, 0, 0, 0);
      a22 = __builtin_amdgcn_mfma_f32_16x16x32_bf16(Aw[kc], Bw[kc], a22, 0, 0, 0);
    }

#pragma unroll
    for (int reg = 0; reg < 4; ++reg) {
      float dy = iA[reg].x - jA4.x, dx = iA[reg].y - jA4.y;
      float s11 = dy * dy + dx * dx;
      float wy_ = iA[reg].z - jA4.z, wx_ = iA[reg].w - jA4.w;
      float s22 = wy_ * wy_ + wx_ * wx_;
      bool m2 = s22 > 256.0f;
      float qD  = fmaxf(iB[reg].x + jB2.y - 2.0f * aD[reg],  1e-12f);
      float qDt = fmaxf(iB[reg].y + jB2.x - 2.0f * aDt[reg], 1e-12f);
      ins4(m2 ? qD  : 25.0f, LD[reg]);
      ins4(m2 ? qDt : 25.0f, LDt[reg]);
      float q11 = fmaxf(iB[reg].x + jB2.x - 2.0f * a11[reg], 1e-12f);
      float k11 = (m2 && s11 > 256.0f) ? q11 : 1e12f;
      if (k11 < SS[reg][7]) {
        float q22 = fmaxf(iB[reg].y + jB2.y - 2.0f * a22[reg], 1e-12f);
        ins8(k11, q22, SS[reg], SP[reg]);
      }
    }
  }

  // ---- butterfly merge across the 16 col-classes (stays within quad) ----
#pragma unroll
  for (int off = 1; off < 16; off <<= 1) {
#pragma unroll
    for (int r = 0; r < 4; ++r) {
      float tv[8], tp[8];
#pragma unroll
      for (int k = 0; k < 4; ++k) tv[k] = __shfl_xor(LD[r][k], off, 64);
#pragma unroll
      for (int k = 0; k < 4; ++k) ins4(tv[k], LD[r]);
#pragma unroll
      for (int k = 0; k < 4; ++k) tv[k] = __shfl_xor(LDt[r][k], off, 64);
#pragma unroll
      for (int k = 0; k < 4; ++k) ins4(tv[k], LDt[r]);
#pragma unroll
      for (int k = 0; k < 8; ++k) {
        tv[k] = __shfl_xor(SS[r][k], off, 64);
        tp[k] = __shfl_xor(SP[r][k], off, 64);
      }
#pragma unroll
      for (int k = 0; k < 8; ++k) ins8(tv[k], tp[k], SS[r], SP[r]);
    }
  }

  // ---- cross-wave merge via LDS ----
  if (c == 0) {
#pragma unroll
    for (int reg = 0; reg < 4; ++reg) {
      float* m = &mergebuf[(quad * 4 + reg) * 96 + wave * 24];
#pragma unroll
      for (int k = 0; k < 4; ++k) { m[k] = LD[reg][k]; m[4 + k] = LDt[reg][k]; }
#pragma unroll
      for (int k = 0; k < 8; ++k) { m[8 + k] = SS[reg][k]; m[16 + k] = SP[reg][k]; }
    }
  }
  __syncthreads();

  float contrib = 0.0f;
  if (tid < 16) {
    float fLD[4], fLDt[4], fSS[8], fSP[8];
#pragma unroll
    for (int k = 0; k < 4; ++k) { fLD[k] = 25.0f; fLDt[k] = 25.0f; }
#pragma unroll
    for (int k = 0; k < 8; ++k) { fSS[k] = 1e12f; fSP[k] = 0.0f; }
    const float* m = &mergebuf[tid * 96];
#pragma unroll
    for (int w = 0; w < 4; ++w) {
      const float* q = m + w * 24;
#pragma unroll
      for (int k = 0; k < 4; ++k) { ins4(q[k], fLD); ins4(q[4 + k], fLDt); }
#pragma unroll
      for (int k = 0; k < 8; ++k) ins8(q[8 + k], q[16 + k], fSS, fSP);
    }
    int gi = base + i0 + tid;
    float pv = posg[gi], vv = visg[gi];
    float t1s = 0.0f, t2s = 0.0f;
#pragma unroll
    for (int k = 0; k < 4; ++k) {
      t1s += fmaxf(1.0f + pv - sqrtf(fLD[k]), 0.0f);
      t2s += fmaxf(1.0f + pv - sqrtf(fLDt[k]), 0.0f);
    }
    float s = 0.0f;
#pragma unroll
    for (int k = 0; k < 8; ++k) {
      if (fSS[k] < 1e10f) {  // (sel_d11 < 1e5)^2
        float d = sqrtf(fSS[k]) - sqrtf(fSP[k]);
        s += d * d;
      }
    }
    contrib = vv * (0.125f * (t1s + t2s) + sqrtf(s + 1e-12f));
  }
  if (tid < 64) {
#pragma unroll
    for (int off = 8; off >= 1; off >>= 1) contrib += __shfl_down(contrib, off, 64);
    if (tid == 0) atomicAdd(&accum[0], contrib);
  }
}

__global__ __launch_bounds__(256) void finalize_kernel(
    const float* __restrict__ vis, const float* __restrict__ acc,
    float* __restrict__ out) {
  __shared__ float red[4];
  float s = 0.0f;
  for (int i = threadIdx.x; i < 2 * NPTS; i += 256) s += vis[i];
#pragma unroll
  for (int off = 32; off >= 1; off >>= 1) s += __shfl_down(s, off, 64);
  if ((threadIdx.x & 63) == 0) red[threadIdx.x >> 6] = s;
  __syncthreads();
  if (threadIdx.x == 0) {
    float denom = red[0] + red[1] + red[2] + red[3] + 1e-8f;
    out[0] = acc[0] / denom;
  }
}

extern "C" void kernel_launch(void* const* d_in, const int* in_sizes, int n_in,
                              void* d_out, int out_size, void* d_ws, size_t ws_size,
                              hipStream_t stream) {
  (void)in_sizes; (void)n_in; (void)out_size; (void)ws_size;
  const float* kp1   = (const float*)d_in[0];
  const float* wkp1  = (const float*)d_in[1];
  const float* desc  = (const float*)d_in[2];
  const float* desc2 = (const float*)d_in[3];
  const float* homo  = (const float*)d_in[4];
  float* ws = (float*)d_ws;
  unsigned short* d1b = (unsigned short*)(ws + OFF_D1B);
  unsigned short* wdb = (unsigned short*)(ws + OFF_WDB);
  float4* jA = (float4*)(ws + OFF_JA);
  float2* jB = (float2*)(ws + OFF_JB);
  float* pos = ws + OFF_POS;
  float* vis = ws + OFF_VIS;
  float* acc = ws + OFF_ACC;

  hipMemsetAsync(acc, 0, 2 * sizeof(float), stream);
  prep_kernel<<<2 * NPTS, 128, 0, stream>>>(kp1, wkp1, desc, desc2, homo,
                                            d1b, wdb, jA, jB, pos, vis);
  loss_main<<<512, 256, 0, stream>>>(d1b, wdb, jA, jB, pos, vis, acc);
  finalize_kernel<<<1, 256, 0, stream>>>(vis, acc, (float*)d_out);
}

// Round 3
// 265.429 us; speedup vs baseline: 5.3193x; 1.1807x over previous
//
#include <hip/hip_runtime.h>
#include <math.h>

#define NPTS 4096
#define CDIM 128
#define FH 120
#define FW 160

typedef __attribute__((ext_vector_type(8))) short short8_t;
typedef __attribute__((ext_vector_type(4))) float float4_t;
typedef __attribute__((ext_vector_type(2))) unsigned short ushort2_t;

// workspace layout (float offsets)
#define OFF_D1B  0                    // 2*4096*128 bf16 = 524288 floats
#define OFF_WDB  524288
#define OFF_JA   1048576              // float4/pt: (ky,kx,wky,wkx)
#define OFF_JB   1081344              // float2/pt: (|d1|^2, |wd|^2)
#define OFF_POS  1097728
#define OFF_VIS  1105920
#define OFF_ACC  1114112

__device__ __forceinline__ unsigned short f2bf(float f) {
  unsigned int u = __float_as_uint(f);
  u = (u + 0x7fffu + ((u >> 16) & 1u)) >> 16;  // RNE, no NaN in this data
  return (unsigned short)u;
}

__device__ __forceinline__ float wavesum(float v) {
#pragma unroll
  for (int off = 1; off < 64; off <<= 1) v += __shfl_xor(v, off, 64);
  return v;
}

// one wave per point; lane handles channels (2*lane, 2*lane+1); shfl-only reductions
__global__ __launch_bounds__(256) void prep_kernel(
    const float* __restrict__ kp1, const float* __restrict__ wkp1,
    const float* __restrict__ desc, const float* __restrict__ desc2,
    const float* __restrict__ homo,
    unsigned short* __restrict__ d1b, unsigned short* __restrict__ wdb,
    float4* __restrict__ jA, float2* __restrict__ jB,
    float* __restrict__ pos, float* __restrict__ vis) {
  const int tid = threadIdx.x;
  const int p = blockIdx.x * 4 + (tid >> 6);   // 0..8191
  const int lane = tid & 63;
  const int b = p >> 12;
  const int c2 = lane * 2;

  float2 v = *(const float2*)(desc + (size_t)p * CDIM + c2);
  float ss = wavesum(v.x * v.x + v.y * v.y);
  float inv = 1.0f / (sqrtf(ss) + 1e-8f);
  float d0 = v.x * inv, d1v = v.y * inv;
  ushort2_t st; st.x = f2bf(d0); st.y = f2bf(d1v);
  *(ushort2_t*)(d1b + (size_t)p * CDIM + c2) = st;
  float n1 = ss * inv * inv;

  float y = wkp1[p * 2 + 0], x = wkp1[p * 2 + 1];
  float gy = fminf(fmaxf(y * 0.125f - 0.5f, 0.0f), (float)(FH - 1));
  float gx = fminf(fmaxf(x * 0.125f - 0.5f, 0.0f), (float)(FW - 1));
  int y0 = (int)floorf(gy); y0 = min(max(y0, 0), FH - 2);
  int x0 = (int)floorf(gx); x0 = min(max(x0, 0), FW - 2);
  float wy = gy - (float)y0, wx = gx - (float)x0;
  float w00 = (1 - wy) * (1 - wx), w01 = (1 - wy) * wx;
  float w10 = wy * (1 - wx), w11 = wy * wx;
  const float* q0 = desc2 + ((size_t)b * CDIM + c2) * (FH * FW) + y0 * FW + x0;
  const float* q1 = q0 + FH * FW;
  float wv0 = q0[0] * w00 + q0[1] * w01 + q0[FW] * w10 + q0[FW + 1] * w11;
  float wv1 = q1[0] * w00 + q1[1] * w01 + q1[FW] * w10 + q1[FW + 1] * w11;
  float ss2 = wavesum(wv0 * wv0 + wv1 * wv1);
  float inv2 = 1.0f / (sqrtf(ss2) + 1e-8f);
  float e0 = wv0 * inv2, e1 = wv1 * inv2;
  ushort2_t sw; sw.x = f2bf(e0); sw.y = f2bf(e1);
  *(ushort2_t*)(wdb + (size_t)p * CDIM + c2) = sw;
  float n2 = ss2 * inv2 * inv2;

  float dd0 = d0 - e0, dd1 = d1v - e1;
  float ssp = wavesum(dd0 * dd0 + dd1 * dd1);

  if (lane == 0) {
    pos[p] = sqrtf(ssp + 1e-12f);
    float ky = kp1[p * 2 + 0], kx = kp1[p * 2 + 1];
    jA[p] = make_float4(ky, kx, y, x);
    jB[p] = make_float2(n1, n2);
    const float* h = homo + b * 9;
    float t0 = h[0] * kx + h[1] * ky + h[2];
    float t1 = h[3] * kx + h[4] * ky + h[5];
    float t2 = h[6] * kx + h[7] * ky + h[8];
    float qx = t0 / (t2 + 1e-8f), qy = t1 / (t2 + 1e-8f);
    vis[p] = (qx >= 0.0f && qx < 1280.0f && qy >= 0.0f && qy < 960.0f) ? 1.0f : 0.0f;
  }
}

// descending insert, caller guards v > L[last]
__device__ __forceinline__ void ins6d(float v, float* L) {
  float cv = v;
#pragma unroll
  for (int k = 0; k < 6; ++k) {
    float o = L[k];
    bool gt = cv > o;
    L[k] = gt ? cv : o;
    cv = gt ? o : cv;
  }
}
__device__ __forceinline__ void ins10d(float v, float* L) {
  float cv = v;
#pragma unroll
  for (int k = 0; k < 10; ++k) {
    float o = L[k];
    bool gt = cv > o;
    L[k] = gt ? cv : o;
    cv = gt ? o : cv;
  }
}

// pack j (12 bits) into low mantissa of score; float ordering preserved to ~2^-12
__device__ __forceinline__ float packkey(float s, int j) {
  return __uint_as_float((__float_as_uint(s) & 0xFFFFF000u) | (unsigned)j);
}

// 512 blocks x 512 threads (8 waves). Block = (batch, 16 anchors = MFMA N-dim).
// Wave w sweeps j in [w*512,(w+1)*512) as MFMA M-dim: per lane 4 j's, ONE anchor.
// Selection in packed score space; masks + d22 deferred to the block epilogue.
__global__ __launch_bounds__(512, 4) void loss_main(
    const unsigned short* __restrict__ d1b, const unsigned short* __restrict__ wdb,
    const float4* __restrict__ jAg, const float2* __restrict__ jBg,
    const float* __restrict__ posg, const float* __restrict__ visg,
    float* __restrict__ accum) {
  __shared__ float mb[8][16][24];   // ladder merge buffer: [wave][anchor][6+6+10 pad 24]
  __shared__ int   sosJ[128];
  __shared__ float sosD11[128], sosD22[128], sosN2i[16];

  const int tid = threadIdx.x;
  const int b = blockIdx.x & 1;
  const int g = blockIdx.x >> 1;          // 0..255
  const int i0 = g * 16;
  const int wave = tid >> 6, lane = tid & 63;
  const int c = lane & 15;                // anchor class (N)
  const int quad = lane >> 4;
  const int base = b * NPTS;

  // B fragments: the 16 anchors' descriptors (kept in regs for the whole sweep)
  short8_t Bd[4], Bw[4];
  {
    const unsigned short* pa = d1b + (size_t)(base + i0 + c) * CDIM + quad * 8;
    const unsigned short* pw = wdb + (size_t)(base + i0 + c) * CDIM + quad * 8;
#pragma unroll
    for (int kc = 0; kc < 4; ++kc) {
      Bd[kc] = *(const short8_t*)(pa + kc * 32);
      Bw[kc] = *(const short8_t*)(pw + kc * 32);
    }
  }

  // per-lane candidate lists (packed keys), descending
  float fD[6], fDt[6], fS[10];
#pragma unroll
  for (int k = 0; k < 6; ++k) { fD[k] = -1e30f; fDt[k] = -1e30f; }
#pragma unroll
  for (int k = 0; k < 10; ++k) fS[k] = -1e30f;

  for (int t = 0; t < 32; ++t) {
    const int j0 = (wave << 9) + (t << 4);      // local j of tile row 0
    const unsigned short* pj1 = d1b + (size_t)(base + j0 + c) * CDIM + quad * 8;
    const unsigned short* pj2 = wdb + (size_t)(base + j0 + c) * CDIM + quad * 8;
    short8_t Ad[4], Aw[4];
#pragma unroll
    for (int kc = 0; kc < 4; ++kc) {
      Ad[kc] = *(const short8_t*)(pj1 + kc * 32);
      Aw[kc] = *(const short8_t*)(pj2 + kc * 32);
    }
    float2 jn[4];
#pragma unroll
    for (int reg = 0; reg < 4; ++reg) jn[reg] = jBg[base + j0 + (quad << 2) + reg];

    float4_t aD = {0, 0, 0, 0}, aDt = {0, 0, 0, 0}, a11 = {0, 0, 0, 0};
#pragma unroll
    for (int kc = 0; kc < 4; ++kc) {
      aD  = __builtin_amdgcn_mfma_f32_16x16x32_bf16(Aw[kc], Bd[kc], aD,  0, 0, 0);  // d1_i·wd_j
      aDt = __builtin_amdgcn_mfma_f32_16x16x32_bf16(Ad[kc], Bw[kc], aDt, 0, 0, 0);  // wd_i·d1_j
      a11 = __builtin_amdgcn_mfma_f32_16x16x32_bf16(Ad[kc], Bd[kc], a11, 0, 0, 0);  // d1_i·d1_j
    }

#pragma unroll
    for (int reg = 0; reg < 4; ++reg) {
      const int jj = j0 + (quad << 2) + reg;   // this acc element's j (M = quad*4+reg)
      float kD  = packkey(fmaf(2.0f, aD[reg],  -jn[reg].y), jj);  // dist2 = n1_i - score
      float kDt = packkey(fmaf(2.0f, aDt[reg], -jn[reg].x), jj);  // dist2 = n2_i - score
      float k11 = packkey(fmaf(2.0f, a11[reg], -jn[reg].x), jj);  // d11^2 = n1_i - score
      if (kD  > fD[5])  ins6d(kD, fD);
      if (kDt > fDt[5]) ins6d(kDt, fDt);
      if (k11 > fS[9])  ins10d(k11, fS);
    }
  }

  // ---- merge the 4 quads (same anchor class) via shfl butterfly (snapshot first) ----
  {
    float tmp[10];
#pragma unroll
    for (int off = 16; off <= 32; off <<= 1) {
#pragma unroll
      for (int k = 0; k < 6; ++k) tmp[k] = fD[k];
#pragma unroll
      for (int k = 0; k < 6; ++k) { float tv = __shfl_xor(tmp[k], off, 64); if (tv > fD[5]) ins6d(tv, fD); }
#pragma unroll
      for (int k = 0; k < 6; ++k) tmp[k] = fDt[k];
#pragma unroll
      for (int k = 0; k < 6; ++k) { float tv = __shfl_xor(tmp[k], off, 64); if (tv > fDt[5]) ins6d(tv, fDt); }
#pragma unroll
      for (int k = 0; k < 10; ++k) tmp[k] = fS[k];
#pragma unroll
      for (int k = 0; k < 10; ++k) { float tv = __shfl_xor(tmp[k], off, 64); if (tv > fS[9]) ins10d(tv, fS); }
    }
  }

  // ---- ladder merge across 8 waves (8 -> 4 -> 2 -> 1) ----
#pragma unroll
  for (int half = 4; half >= 1; half >>= 1) {
    if (wave >= half && wave < 2 * half && lane < 16) {
      float* m = &mb[wave][lane][0];
#pragma unroll
      for (int k = 0; k < 6; ++k) { m[k] = fD[k]; m[6 + k] = fDt[k]; }
#pragma unroll
      for (int k = 0; k < 10; ++k) m[12 + k] = fS[k];
    }
    __syncthreads();
    if (wave < half && lane < 16) {
      const float* m = &mb[wave + half][lane][0];
#pragma unroll
      for (int k = 0; k < 6; ++k) { float tv = m[k]; if (tv > fD[5]) ins6d(tv, fD); }
#pragma unroll
      for (int k = 0; k < 6; ++k) { float tv = m[6 + k]; if (tv > fDt[5]) ins6d(tv, fDt); }
#pragma unroll
      for (int k = 0; k < 10; ++k) { float tv = m[12 + k]; if (tv > fS[9]) ins10d(tv, fS); }
    }
  }

  // ---- post-filter (masks) on <=22 candidates per anchor, threads 0..15 ----
  float t1s = 0.0f, t2s = 0.0f, pv = 0.0f, vv = 0.0f;
  if (tid < 16) {
    const int gi = base + i0 + tid;
    const float4 own = jAg[gi];
    const float2 nb = jBg[gi];
    pv = posg[gi]; vv = visg[gi];
    int got = 0;
#pragma unroll
    for (int k = 0; k < 6; ++k) {
      int j = (int)(__float_as_uint(fD[k]) & 0xFFFu);
      float4 jc = jAg[base + j];
      float dz = own.z - jc.z, dw = own.w - jc.w;
      if (got < 4 && dz * dz + dw * dw > 256.0f) {
        float d2 = nb.x - fD[k];
        t1s += fmaxf(1.0f + pv - sqrtf(fmaxf(d2, 1e-12f)), 0.0f);
        got++;
      }
    }
    got = 0;
#pragma unroll
    for (int k = 0; k < 6; ++k) {
      int j = (int)(__float_as_uint(fDt[k]) & 0xFFFu);
      float4 jc = jAg[base + j];
      float dz = own.z - jc.z, dw = own.w - jc.w;
      if (got < 4 && dz * dz + dw * dw > 256.0f) {
        float d2 = nb.y - fDt[k];
        t2s += fmaxf(1.0f + pv - sqrtf(fmaxf(d2, 1e-12f)), 0.0f);
        got++;
      }
    }
    int m = 0;
#pragma unroll
    for (int k = 0; k < 10; ++k) {
      int j = (int)(__float_as_uint(fS[k]) & 0xFFFu);
      float4 jc = jAg[base + j];
      float ay = own.x - jc.x, ax = own.y - jc.y;
      float wz = own.z - jc.z, ww = own.w - jc.w;
      if (m < 8 && ay * ay + ax * ax > 256.0f && wz * wz + ww * ww > 256.0f) {
        sosJ[tid * 8 + m] = j;
        sosD11[tid * 8 + m] = sqrtf(fmaxf(nb.x - fS[k], 1e-12f));
        m++;
      }
    }
    for (int k = m; k < 8; ++k) sosJ[tid * 8 + k] = -1;
    sosN2i[tid] = nb.y;
  }
  __syncthreads();

  // ---- d22 for SOS survivors: 128 slots x 4 threads, 32ch each ----
  {
    const int slot = tid >> 2, part = tid & 3;
    const int j = sosJ[slot];
    float dot = 0.0f;
    if (j >= 0) {
      const int a = slot >> 3;
      const unsigned int* pi = (const unsigned int*)(wdb + (size_t)(base + i0 + a) * CDIM + part * 32);
      const unsigned int* pj = (const unsigned int*)(wdb + (size_t)(base + j) * CDIM + part * 32);
#pragma unroll
      for (int q = 0; q < 16; ++q) {
        unsigned int ui = pi[q], uj = pj[q];
        float xl = __uint_as_float(ui << 16), xh = __uint_as_float(ui & 0xFFFF0000u);
        float yl = __uint_as_float(uj << 16), yh = __uint_as_float(uj & 0xFFFF0000u);
        dot = fmaf(xl, yl, dot);
        dot = fmaf(xh, yh, dot);
      }
    }
    dot += __shfl_xor(dot, 1, 64);
    dot += __shfl_xor(dot, 2, 64);
    if (part == 0 && j >= 0) {
      float n2j = jBg[base + j].y;
      float d22sq = sosN2i[slot >> 3] + n2j - 2.0f * dot;
      sosD22[slot] = sqrtf(fmaxf(d22sq, 1e-12f));
    }
  }
  __syncthreads();

  float contrib = 0.0f;
  if (tid < 16) {
    float s = 0.0f;
#pragma unroll
    for (int k = 0; k < 8; ++k) {
      if (sosJ[tid * 8 + k] >= 0) {
        float d = sosD11[tid * 8 + k] - sosD22[tid * 8 + k];
        s = fmaf(d, d, s);
      }
    }
    float sos_i = sqrtf(s + 1e-12f);
    contrib = vv * (0.125f * (t1s + t2s) + sos_i);
  }
  if (wave == 0) {
#pragma unroll
    for (int off = 1; off < 16; off <<= 1) contrib += __shfl_xor(contrib, off, 64);
    if (tid == 0) atomicAdd(&accum[0], contrib);
  }
}

__global__ __launch_bounds__(256) void finalize_kernel(
    const float* __restrict__ vis, const float* __restrict__ acc,
    float* __restrict__ out) {
  __shared__ float red[4];
  float s = 0.0f;
  for (int i = threadIdx.x; i < 2 * NPTS; i += 256) s += vis[i];
#pragma unroll
  for (int off = 32; off >= 1; off >>= 1) s += __shfl_down(s, off, 64);
  if ((threadIdx.x & 63) == 0) red[threadIdx.x >> 6] = s;
  __syncthreads();
  if (threadIdx.x == 0) {
    float denom = red[0] + red[1] + red[2] + red[3] + 1e-8f;
    out[0] = acc[0] / denom;
  }
}

extern "C" void kernel_launch(void* const* d_in, const int* in_sizes, int n_in,
                              void* d_out, int out_size, void* d_ws, size_t ws_size,
                              hipStream_t stream) {
  (void)in_sizes; (void)n_in; (void)out_size; (void)ws_size;
  const float* kp1   = (const float*)d_in[0];
  const float* wkp1  = (const float*)d_in[1];
  const float* desc  = (const float*)d_in[2];
  const float* desc2 = (const float*)d_in[3];
  const float* homo  = (const float*)d_in[4];
  float* ws = (float*)d_ws;
  unsigned short* d1b = (unsigned short*)(ws + OFF_D1B);
  unsigned short* wdb = (unsigned short*)(ws + OFF_WDB);
  float4* jA = (float4*)(ws + OFF_JA);
  float2* jB = (float2*)(ws + OFF_JB);
  float* pos = ws + OFF_POS;
  float* vis = ws + OFF_VIS;
  float* acc = ws + OFF_ACC;

  hipMemsetAsync(acc, 0, 2 * sizeof(float), stream);
  prep_kernel<<<2048, 256, 0, stream>>>(kp1, wkp1, desc, desc2, homo,
                                        d1b, wdb, jA, jB, pos, vis);
  loss_main<<<512, 512, 0, stream>>>(d1b, wdb, jA, jB, pos, vis, acc);
  finalize_kernel<<<1, 256, 0, stream>>>(vis, acc, (float*)d_out);
}